// Round 13
// baseline (384.193 us; speedup 1.0000x reference)
//
#include <hip/hip_runtime.h>
#include <cstdint>
#include <cstddef>

#define N_INST 131072
#define D_EMB  512
#define ATT    128
#define NBAGS  256
#define NZ1    32          // Z1 shard count

typedef __attribute__((ext_vector_type(8))) short  bf16x8;
typedef __attribute__((ext_vector_type(4))) float  f32x4;

// ---------------- workspace layout (floats) ----------------
// [0..32)       Z1 shards
// [32]          Z2
// [64..576)     v[512]   = W_c @ w_out (folded classifier)
// [1024..1280)  e2[256]
// [1536..2048)  outer[512]
// [4096..36864) Wt bf16 [128][512] (W_a1 transposed, n-major)
// [36864..1085440) rawr[8][256][512]  (replica-sharded bag accumulators)

__device__ inline unsigned short f2b(float f) {
    unsigned u = __builtin_bit_cast(unsigned, f);
    u += 0x7FFFu + ((u >> 16) & 1u);          // RNE
    return (unsigned short)(u >> 16);
}

__device__ inline float fast_tanh(float x) {
    float e = __expf(2.f * x);                // +inf/0 at extremes -> exact +-1
    return 1.f - 2.f / (e + 1.f);
}

// ============ prep: Wt[n][k] = bf16(W_a1[k][n]) ============
__global__ __launch_bounds__(256) void k_prep_wt(
    const float* __restrict__ Wa1, unsigned short* __restrict__ Wt)
{
    const int n = blockIdx.x;
    for (int k = threadIdx.x; k < D_EMB; k += 256)
        Wt[(size_t)n * D_EMB + k] = f2b(Wa1[(size_t)k * ATT + n]);
}

// ============ K1: zero-LDS, zero-barrier, wave-independent fused MIL =========
// 1024 blocks x 256 thr; each of the 4096 waves owns 32 contiguous instances
// (2 tiles of 16) and runs fully independently: A-frags loaded straight from
// global fp32 (coalesced 128B/row), B-frags streamed from L2-hot Wt, score
// reduction via shfl only, phase-2 re-reads the wave's own rows (L2/L3-hot)
// with register segment-carry. 16 waves/CU streaming with no sync coupling --
// attacks the measured BW-per-wave wall (~0.25 TB/s/wave across r3-r12).
__global__ __launch_bounds__(256, 4) void k_att1(
    const float* __restrict__ emb, const int* __restrict__ lab,
    const unsigned short* __restrict__ Wt, const float* __restrict__ ba1,
    const float* __restrict__ wo1, const float* __restrict__ bo1,
    float* __restrict__ rawr, int R, float* __restrict__ Z1s)
{
    const int t  = threadIdx.x;
    const int w  = t >> 6;
    const int l  = t & 63;
    const int l4 = l & 15;
    const int h4 = l >> 4;                    // 0..3
    const int gw = blockIdx.x * 4 + w;        // global wave id, 0..4095
    const size_t ib = (size_t)gw * 32;        // 32 contiguous instances
    float* __restrict__ raw = rawr + (size_t)(blockIdx.x % R) * (NBAGS * D_EMB);

    const float bo = bo1[0];

    int   cur_bag = -1;
    float c0 = 0.f, c1 = 0.f, c2 = 0.f, c3 = 0.f;
    float c4 = 0.f, c5 = 0.f, c6 = 0.f, c7 = 0.f;
    float z1acc = 0.f;

    #pragma unroll
    for (int tt = 0; tt < 2; ++tt) {
        const size_t i0 = ib + tt * 16;

        // ---- score GEMM: A direct from global fp32, B from L2-hot Wt ----
        f32x4 acc[8];
        #pragma unroll
        for (int nt = 0; nt < 8; ++nt) acc[nt] = (f32x4){0.f, 0.f, 0.f, 0.f};

        #pragma unroll
        for (int ks = 0; ks < 16; ++ks) {
            const float* ap = &emb[(i0 + l4) * D_EMB + 32 * ks + 8 * h4];
            float4 fa = *reinterpret_cast<const float4*>(ap);
            float4 fb = *reinterpret_cast<const float4*>(ap + 4);
            bf16x8 af;
            af[0] = (short)f2b(fa.x); af[1] = (short)f2b(fa.y);
            af[2] = (short)f2b(fa.z); af[3] = (short)f2b(fa.w);
            af[4] = (short)f2b(fb.x); af[5] = (short)f2b(fb.y);
            af[6] = (short)f2b(fb.z); af[7] = (short)f2b(fb.w);
            #pragma unroll
            for (int nt = 0; nt < 8; ++nt) {
                bf16x8 bf = *reinterpret_cast<const bf16x8*>(
                    &Wt[(size_t)(l4 + 16 * nt) * D_EMB + 32 * ks + 8 * h4]);
                acc[nt] = __builtin_amdgcn_mfma_f32_16x16x32_bf16(
                    af, bf, acc[nt], 0, 0, 0);
            }
        }

        // ---- epilogue: row scores via shfl-only reduction ----
        // C layout: col = l4 + 16nt, row = 4h4 + reg (validated r2)
        float s4[4];
        #pragma unroll
        for (int reg = 0; reg < 4; ++reg) {
            float p = 0.f;
            #pragma unroll
            for (int nt = 0; nt < 8; ++nt) {
                int cidx = l4 + 16 * nt;
                p += fast_tanh(acc[nt][reg] + ba1[cidx]) * wo1[cidx];
            }
            p += __shfl_xor(p, 1);
            p += __shfl_xor(p, 2);
            p += __shfl_xor(p, 4);
            p += __shfl_xor(p, 8);            // lanes 16h4..16h4+15 now hold row 4h4+reg
            float sg = 1.f / (1.f + __expf(-(p + bo)));   // in (0,1): no max-sub
            s4[reg] = __expf(sg);
        }
        if (l4 == 0) z1acc += s4[0] + s4[1] + s4[2] + s4[3];

        // ---- phase 2: weighted segment sum; wave's rows are L2/L3-hot ----
        // lane owns dims 8l..8l+7; labels sorted -> wave-uniform branch.
        int lv = lab[i0 + (l & 15)];          // lane r (r<16) holds lab[i0+r]
        #pragma unroll
        for (int r = 0; r < 16; ++r) {
            int   bag = __shfl(lv, r);
            float s   = __shfl(s4[r & 3], (r >> 2) * 16);
            if (bag != cur_bag) {
                if (cur_bag >= 0) {
                    float* dst = &raw[cur_bag * D_EMB + 8 * l];
                    atomicAdd(dst + 0, c0); atomicAdd(dst + 1, c1);
                    atomicAdd(dst + 2, c2); atomicAdd(dst + 3, c3);
                    atomicAdd(dst + 4, c4); atomicAdd(dst + 5, c5);
                    atomicAdd(dst + 6, c6); atomicAdd(dst + 7, c7);
                }
                c0 = c1 = c2 = c3 = c4 = c5 = c6 = c7 = 0.f;
                cur_bag = bag;
            }
            const float* ep = &emb[(i0 + r) * D_EMB + 8 * l];
            float4 e0 = *reinterpret_cast<const float4*>(ep);
            float4 e1 = *reinterpret_cast<const float4*>(ep + 4);
            c0 = fmaf(s, e0.x, c0); c1 = fmaf(s, e0.y, c1);
            c2 = fmaf(s, e0.z, c2); c3 = fmaf(s, e0.w, c3);
            c4 = fmaf(s, e1.x, c4); c5 = fmaf(s, e1.y, c5);
            c6 = fmaf(s, e1.z, c6); c7 = fmaf(s, e1.w, c7);
        }
    }

    // ---- final flush + sharded Z1 ----
    if (cur_bag >= 0) {
        float* dst = &raw[cur_bag * D_EMB + 8 * l];
        atomicAdd(dst + 0, c0); atomicAdd(dst + 1, c1);
        atomicAdd(dst + 2, c2); atomicAdd(dst + 3, c3);
        atomicAdd(dst + 4, c4); atomicAdd(dst + 5, c5);
        atomicAdd(dst + 6, c6); atomicAdd(dst + 7, c7);
    }
    z1acc += __shfl_xor(z1acc, 16);
    z1acc += __shfl_xor(z1acc, 32);           // lanes l4==0 all hold wave sum
    if (l == 0) atomicAdd(&Z1s[gw & (NZ1 - 1)], z1acc);
}

// ============ K2: replica-sum + normalize + bag-level attention ============
__global__ __launch_bounds__(128) void k_att2(
    const float* __restrict__ Wa2, const float* __restrict__ ba2,
    const float* __restrict__ wo2, const float* __restrict__ bo2,
    float* __restrict__ rawr, int R, const float* __restrict__ Z1s,
    float* __restrict__ e2, float* __restrict__ Z2)
{
    __shared__ float sec[D_EMB];
    __shared__ float hh[2];
    const int b = blockIdx.x;
    const int t = threadIdx.x;
    float zsum = 0.f;
    #pragma unroll
    for (int i = 0; i < NZ1; ++i) zsum += Z1s[i];
    const float zinv = 1.f / zsum;
    for (int d = t; d < D_EMB; d += 128) {
        float s = 0.f;
        for (int r = 0; r < R; ++r)
            s += rawr[(size_t)r * (NBAGS * D_EMB) + b * D_EMB + d];
        float v = s * zinv;
        rawr[b * D_EMB + d] = v;           // normalized into replica 0
        sec[d] = v;
    }
    __syncthreads();
    float dot = 0.f;
    #pragma unroll 8
    for (int d = 0; d < D_EMB; ++d) dot = fmaf(sec[d], Wa2[d * ATT + t], dot);
    float h = fast_tanh(dot + ba2[t]) * wo2[t];
    #pragma unroll
    for (int m = 1; m < 64; m <<= 1) h += __shfl_xor(h, m);
    if ((t & 63) == 0) hh[t >> 6] = h;
    __syncthreads();
    if (t == 0) {
        float a  = hh[0] + hh[1] + bo2[0];
        float sg = 1.f / (1.f + __expf(-a));
        float e  = __expf(sg);
        e2[b] = e;
        atomicAdd(Z2, e);
    }
}

// ============ Kv: v = W_c @ w_out ============
__global__ __launch_bounds__(256) void k_v(
    const float* __restrict__ Wc, const float* __restrict__ wout,
    float* __restrict__ v)
{
    const int t   = threadIdx.x;
    const int row = blockIdx.x * 8 + (t >> 5);
    const int l   = t & 31;
    float s = 0.f;
    #pragma unroll 4
    for (int c = l; c < 512; c += 32) s = fmaf(Wc[(size_t)row * 512 + c], wout[c], s);
    #pragma unroll
    for (int m = 1; m < 32; m <<= 1) s += __shfl_xor(s, m);
    if (l == 0) v[row] = s;
}

// ============ pool: outer_raw = sum_b e2[b] * raw0[b][:] (8 blocks) ===========
__global__ __launch_bounds__(256) void k_pool(
    const float* __restrict__ raw, const float* __restrict__ e2,
    float* __restrict__ outer)
{
    const int t  = threadIdx.x;
    const int b0 = blockIdx.x * 32;
    float o0 = 0.f, o1 = 0.f;
    for (int b = b0; b < b0 + 32; ++b) {
        float wgt = e2[b];
        float2 r = *reinterpret_cast<const float2*>(&raw[b * D_EMB + 2 * t]);
        o0 = fmaf(wgt, r.x, o0);
        o1 = fmaf(wgt, r.y, o1);
    }
    atomicAdd(&outer[2 * t], o0);
    atomicAdd(&outer[2 * t + 1], o1);
}

// ============ classifier: pred = sigmoid(outer/Z2 . v + bc . wout + bout) ====
__global__ __launch_bounds__(256) void k_cls(
    const float* __restrict__ outer, const float* __restrict__ Z2,
    const float* __restrict__ v, const float* __restrict__ bc,
    const float* __restrict__ wout, const float* __restrict__ bout,
    float* __restrict__ out)
{
    __shared__ float pp[4];
    const int t = threadIdx.x;
    const float z2inv = 1.f / Z2[0];
    float p = (outer[2 * t] * v[2 * t] + outer[2 * t + 1] * v[2 * t + 1]) * z2inv
            + bc[2 * t] * wout[2 * t] + bc[2 * t + 1] * wout[2 * t + 1];
    #pragma unroll
    for (int m = 1; m < 64; m <<= 1) p += __shfl_xor(p, m);
    if ((t & 63) == 0) pp[t >> 6] = p;
    __syncthreads();
    if (t == 0) {
        float s = pp[0] + pp[1] + pp[2] + pp[3] + bout[0];
        out[0] = 1.f / (1.f + __expf(-s));
    }
}

extern "C" void kernel_launch(void* const* d_in, const int* in_sizes, int n_in,
                              void* d_out, int out_size, void* d_ws, size_t ws_size,
                              hipStream_t stream)
{
    const float* emb  = (const float*)d_in[0];
    const int*   lab  = (const int*)d_in[1];
    const float* Wa1  = (const float*)d_in[2];
    const float* ba1  = (const float*)d_in[3];
    const float* wo1  = (const float*)d_in[4];
    const float* bo1  = (const float*)d_in[5];
    const float* Wa2  = (const float*)d_in[6];
    const float* ba2  = (const float*)d_in[7];
    const float* wo2  = (const float*)d_in[8];
    const float* bo2  = (const float*)d_in[9];
    const float* Wc   = (const float*)d_in[10];
    const float* bc   = (const float*)d_in[11];
    const float* wout = (const float*)d_in[12];
    const float* bout = (const float*)d_in[13];

    float* ws    = (float*)d_ws;
    float* Z1s   = ws + 0;        // 32 shards
    float* Z2    = ws + 32;
    float* v     = ws + 64;
    float* e2    = ws + 1024;
    float* outer = ws + 1536;
    unsigned short* Wt = (unsigned short*)(ws + 4096);
    float* rawr  = ws + 36864;

    // replica count: 8 if workspace allows (XCD-local atomics), else 1
    const size_t need8 = ((size_t)36864 + 8u * NBAGS * D_EMB) * sizeof(float);
    const int R = (ws_size >= need8) ? 8 : 1;

    // zero scalars + replica accumulators (harness does not re-poison)
    hipMemsetAsync(d_ws, 0, ((size_t)36864 + (size_t)R * NBAGS * D_EMB) * sizeof(float), stream);

    hipLaunchKernelGGL(k_prep_wt, dim3(ATT),   dim3(256), 0, stream, Wa1, Wt);
    hipLaunchKernelGGL(k_v,       dim3(64),    dim3(256), 0, stream, Wc, wout, v);
    hipLaunchKernelGGL(k_att1,    dim3(1024),  dim3(256), 0, stream,
                       emb, lab, Wt, ba1, wo1, bo1, rawr, R, Z1s);
    hipLaunchKernelGGL(k_att2,    dim3(NBAGS), dim3(128), 0, stream,
                       Wa2, ba2, wo2, bo2, rawr, R, Z1s, e2, Z2);
    hipLaunchKernelGGL(k_pool,    dim3(8),     dim3(256), 0, stream,
                       rawr, e2, outer);
    hipLaunchKernelGGL(k_cls,     dim3(1),     dim3(256), 0, stream,
                       outer, Z2, v, bc, wout, bout, (float*)d_out);
}

// Round 14
// 139.903 us; speedup vs baseline: 2.7461x; 2.7461x over previous
//
#include <hip/hip_runtime.h>
#include <cstdint>
#include <cstddef>

#define N_INST 131072
#define D_EMB  512
#define ATT    128
#define NBAGS  256
#define TILE_I 32
#define LDA    520   // padded bf16 row stride (1040 B)
#define NBLK   512   // persistent blocks (2 per CU)
#define NTILES (N_INST / TILE_I)   // 4096
#define TPB    (NTILES / NBLK)     // 8 CONTIGUOUS tiles per block
#define NZ1    32

typedef __attribute__((ext_vector_type(8))) short  bf16x8;
typedef __attribute__((ext_vector_type(4))) float  f32x4;
typedef __attribute__((ext_vector_type(4))) unsigned short u16x4;

// ---------------- workspace layout (floats) ----------------
// [0..32)       Z1 shards
// [32]          Z2
// [64..576)     v[512]   = W_c @ w_out (folded classifier)
// [1024..1280)  e2[256]
// [1536..2048)  outer[512]
// [4096..36864) Wt bf16 [128][512] (W_a1 transposed, n-major)
// [36864..1085440) rawr[8][256][512]  (replica-sharded bag accumulators)

__device__ inline unsigned short f2b(float f) {
    unsigned u = __builtin_bit_cast(unsigned, f);
    u += 0x7FFFu + ((u >> 16) & 1u);          // RNE
    return (unsigned short)(u >> 16);
}

__device__ inline float fast_tanh(float x) {
    float e = __expf(2.f * x);                // +inf/0 at extremes -> exact +-1
    return 1.f - 2.f / (e + 1.f);
}

// ============ prep: Wt[n][k] = bf16(W_a1[k][n]) ============
__global__ __launch_bounds__(256) void k_prep_wt(
    const float* __restrict__ Wa1, unsigned short* __restrict__ Wt)
{
    const int n = blockIdx.x;
    for (int k = threadIdx.x; k < D_EMB; k += 256)
        Wt[(size_t)n * D_EMB + k] = f2b(Wa1[(size_t)k * ATT + n]);
}

// ============ K1: r8 structure + contiguous tiles + atomic-carry fix =========
// 512 blocks x 256 thr (4 waves), 2 blocks/CU. Each block owns 8 CONTIGUOUS
// tiles (256 contiguous instances). Phase-2 carries segment sums in registers
// across tiles; flushes only at bag boundaries (~2/block total). Adjacent
// blocks (which share a bag) map to different replicas (blockIdx%R) -> no
// same-address atomic contention. This attacks the +6.9us/tile phase-2
// marginal the r10 ablation isolated (contended-atomic drain at barriers).
__global__ __launch_bounds__(256, 2) void k_att1(
    const float* __restrict__ emb, const int* __restrict__ lab,
    const unsigned short* __restrict__ Wt, const float* __restrict__ ba1,
    const float* __restrict__ wo1, const float* __restrict__ bo1,
    float* __restrict__ rawr, int R, float* __restrict__ Z1s)
{
    __shared__ unsigned short Ash[2][TILE_I * LDA];   // 2 x 33280 B
    __shared__ float att4[4][TILE_I];
    __shared__ float sval[TILE_I];
    __shared__ int   labs[2][TILE_I];

    const int t  = threadIdx.x;
    const int w  = t >> 6;        // 0..3
    const int l  = t & 63;
    const int l4 = l & 15;
    const int h4 = l >> 4;        // 0..3
    const int n0 = 16 * (2 * w) + l4;
    const int n1 = 16 * (2 * w + 1) + l4;
    const size_t tile0 = (size_t)blockIdx.x * TPB;
    float* __restrict__ raw = rawr + (size_t)(blockIdx.x % R) * (NBAGS * D_EMB);

    const float ba1v0 = ba1[n0], ba1v1 = ba1[n1];
    const float wo1v0 = wo1[n0], wo1v1 = wo1[n1];

    // ---- prologue: stage tile0 into buf 0 ----
    {
        const size_t i0 = tile0 * TILE_I;
        float4 v[16];
        #pragma unroll
        for (int j = 0; j < 16; ++j) {
            int idx = j * 256 + t;           // float4 idx in [0, 4096)
            int row = idx >> 7;              // 128 float4 per row
            int c4  = (idx & 127) * 4;
            v[j] = *reinterpret_cast<const float4*>(&emb[(i0 + row) * D_EMB + c4]);
        }
        if (t < TILE_I) labs[0][t] = lab[i0 + t];
        #pragma unroll
        for (int j = 0; j < 16; ++j) {
            int idx = j * 256 + t;
            int row = idx >> 7;
            int c4  = (idx & 127) * 4;
            u16x4 b = { f2b(v[j].x), f2b(v[j].y), f2b(v[j].z), f2b(v[j].w) };
            *reinterpret_cast<u16x4*>(&Ash[0][row * LDA + c4]) = b;
        }
    }
    __syncthreads();

    int   cur_bag = -1;
    float ar0 = 0.f, ar1 = 0.f;   // register carry: dims 2t, 2t+1
    float z1acc = 0.f;
    int   p = 0;

    for (int it = 0; it < TPB; ++it) {
        const bool hasNext = (it + 1 < TPB);
        const size_t i0n = (tile0 + it + 1) * TILE_I;

        // ---- (1) prefetch next tile's A (in flight through GEMM) ----
        float4 v[16];
        int nlab = 0;
        if (hasNext) {
            #pragma unroll
            for (int j = 0; j < 16; ++j) {
                int idx = j * 256 + t;
                int row = idx >> 7;
                int c4  = (idx & 127) * 4;
                v[j] = *reinterpret_cast<const float4*>(
                    &emb[(i0n + row) * D_EMB + c4]);
            }
            if (t < TILE_I) nlab = lab[i0n + t];
        }

        // ---- (2) score GEMM on Ash[p]; B per-ks from L2-hot Wt ----
        f32x4 acc00 = {0.f,0.f,0.f,0.f}, acc01 = {0.f,0.f,0.f,0.f};
        f32x4 acc10 = {0.f,0.f,0.f,0.f}, acc11 = {0.f,0.f,0.f,0.f};
        #pragma unroll
        for (int ks = 0; ks < 16; ++ks) {
            bf16x8 b0 = *reinterpret_cast<const bf16x8*>(
                &Wt[(size_t)n0 * D_EMB + 32 * ks + 8 * h4]);
            bf16x8 b1 = *reinterpret_cast<const bf16x8*>(
                &Wt[(size_t)n1 * D_EMB + 32 * ks + 8 * h4]);
            bf16x8 a0 = *reinterpret_cast<const bf16x8*>(
                &Ash[p][(l4) * LDA + 32 * ks + 8 * h4]);
            bf16x8 a1 = *reinterpret_cast<const bf16x8*>(
                &Ash[p][(16 + l4) * LDA + 32 * ks + 8 * h4]);
            acc00 = __builtin_amdgcn_mfma_f32_16x16x32_bf16(a0, b0, acc00, 0, 0, 0);
            acc01 = __builtin_amdgcn_mfma_f32_16x16x32_bf16(a0, b1, acc01, 0, 0, 0);
            acc10 = __builtin_amdgcn_mfma_f32_16x16x32_bf16(a1, b0, acc10, 0, 0, 0);
            acc11 = __builtin_amdgcn_mfma_f32_16x16x32_bf16(a1, b1, acc11, 0, 0, 0);
        }

        // ---- (3) epilogue: per-wave score partials ----
        // C layout: col = l4 + 16*(2w+nt), row = 16rt + 4h4 + reg (validated r2)
        #pragma unroll
        for (int rt = 0; rt < 2; ++rt) {
            #pragma unroll
            for (int reg = 0; reg < 4; ++reg) {
                float pp = fast_tanh((rt ? acc10[reg] : acc00[reg]) + ba1v0) * wo1v0
                         + fast_tanh((rt ? acc11[reg] : acc01[reg]) + ba1v1) * wo1v1;
                pp += __shfl_xor(pp, 1);
                pp += __shfl_xor(pp, 2);
                pp += __shfl_xor(pp, 4);
                pp += __shfl_xor(pp, 8);
                if (l4 == 0) att4[w][16 * rt + 4 * h4 + reg] = pp;
            }
        }

        // ---- (4) dbuf store pre-B1: Ash[p^1]/labs[p^1] free since prev B3 ----
        if (hasNext) {
            #pragma unroll
            for (int j = 0; j < 16; ++j) {
                int idx = j * 256 + t;
                int row = idx >> 7;
                int c4  = (idx & 127) * 4;
                u16x4 b = { f2b(v[j].x), f2b(v[j].y), f2b(v[j].z), f2b(v[j].w) };
                *reinterpret_cast<u16x4*>(&Ash[p ^ 1][row * LDA + c4]) = b;
            }
            if (t < TILE_I) labs[p ^ 1][t] = nlab;
        }
        __syncthreads();                                   // B1

        // ---- (5) softmax (t<32) ----
        if (t < TILE_I) {
            float a  = att4[0][t] + att4[1][t] + att4[2][t] + att4[3][t] + bo1[0];
            float sg = 1.f / (1.f + __expf(-a));   // in (0,1): exp needs no max-sub
            float s  = __expf(sg);
            sval[t]  = s;
            float z = s;
            z += __shfl_xor(z, 1);
            z += __shfl_xor(z, 2);
            z += __shfl_xor(z, 4);
            z += __shfl_xor(z, 8);
            z += __shfl_xor(z, 16);
            if (t == 0) z1acc += z;
        }
        __syncthreads();                                   // B2

        // ---- (6) phase 2: weighted segment sum from LDS, register carry ----
        // thread t owns dims {2t, 2t+1}; one 4B read gives both (bf16 pair).
        {
            int s0 = 0;
            while (s0 < TILE_I) {
                int bag = labs[p][s0];
                int s1 = s0 + 1;
                while (s1 < TILE_I && labs[p][s1] == bag) ++s1;
                if (bag != cur_bag) {
                    if (cur_bag >= 0) {
                        atomicAdd(&raw[cur_bag * D_EMB + 2 * t], ar0);
                        atomicAdd(&raw[cur_bag * D_EMB + 2 * t + 1], ar1);
                    }
                    ar0 = 0.f; ar1 = 0.f; cur_bag = bag;
                }
                for (int ii = s0; ii < s1; ++ii) {
                    unsigned u = *reinterpret_cast<const unsigned*>(
                        &Ash[p][(size_t)ii * LDA + 2 * t]);
                    float lo = __builtin_bit_cast(float, u << 16);
                    float hi = __builtin_bit_cast(float, u & 0xffff0000u);
                    float s  = sval[ii];
                    ar0 = fmaf(s, lo, ar0);
                    ar1 = fmaf(s, hi, ar1);
                }
                s0 = s1;
            }
        }
        __syncthreads();                                   // B3: LDS reads done
        p ^= 1;
    }

    if (cur_bag >= 0) {
        atomicAdd(&raw[cur_bag * D_EMB + 2 * t], ar0);
        atomicAdd(&raw[cur_bag * D_EMB + 2 * t + 1], ar1);
    }
    if (t == 0) atomicAdd(&Z1s[blockIdx.x & (NZ1 - 1)], z1acc);
}

// ============ K2: replica-sum + normalize + bag-level attention ============
__global__ __launch_bounds__(128) void k_att2(
    const float* __restrict__ Wa2, const float* __restrict__ ba2,
    const float* __restrict__ wo2, const float* __restrict__ bo2,
    float* __restrict__ rawr, int R, const float* __restrict__ Z1s,
    float* __restrict__ e2, float* __restrict__ Z2)
{
    __shared__ float sec[D_EMB];
    __shared__ float hh[2];
    const int b = blockIdx.x;
    const int t = threadIdx.x;
    float zsum = 0.f;
    #pragma unroll
    for (int i = 0; i < NZ1; ++i) zsum += Z1s[i];
    const float zinv = 1.f / zsum;
    for (int d = t; d < D_EMB; d += 128) {
        float s = 0.f;
        for (int r = 0; r < R; ++r)
            s += rawr[(size_t)r * (NBAGS * D_EMB) + b * D_EMB + d];
        float v = s * zinv;
        rawr[b * D_EMB + d] = v;           // normalized into replica 0
        sec[d] = v;
    }
    __syncthreads();
    float dot = 0.f;
    #pragma unroll 8
    for (int d = 0; d < D_EMB; ++d) dot = fmaf(sec[d], Wa2[d * ATT + t], dot);
    float h = fast_tanh(dot + ba2[t]) * wo2[t];
    #pragma unroll
    for (int m = 1; m < 64; m <<= 1) h += __shfl_xor(h, m);
    if ((t & 63) == 0) hh[t >> 6] = h;
    __syncthreads();
    if (t == 0) {
        float a  = hh[0] + hh[1] + bo2[0];
        float sg = 1.f / (1.f + __expf(-a));
        float e  = __expf(sg);
        e2[b] = e;
        atomicAdd(Z2, e);
    }
}

// ============ Kv: v = W_c @ w_out ============
__global__ __launch_bounds__(256) void k_v(
    const float* __restrict__ Wc, const float* __restrict__ wout,
    float* __restrict__ v)
{
    const int t   = threadIdx.x;
    const int row = blockIdx.x * 8 + (t >> 5);
    const int l   = t & 31;
    float s = 0.f;
    #pragma unroll 4
    for (int c = l; c < 512; c += 32) s = fmaf(Wc[(size_t)row * 512 + c], wout[c], s);
    #pragma unroll
    for (int m = 1; m < 32; m <<= 1) s += __shfl_xor(s, m);
    if (l == 0) v[row] = s;
}

// ============ pool: outer_raw = sum_b e2[b] * raw0[b][:] (8 blocks) ===========
__global__ __launch_bounds__(256) void k_pool(
    const float* __restrict__ raw, const float* __restrict__ e2,
    float* __restrict__ outer)
{
    const int t  = threadIdx.x;
    const int b0 = blockIdx.x * 32;
    float o0 = 0.f, o1 = 0.f;
    for (int b = b0; b < b0 + 32; ++b) {
        float wgt = e2[b];
        float2 r = *reinterpret_cast<const float2*>(&raw[b * D_EMB + 2 * t]);
        o0 = fmaf(wgt, r.x, o0);
        o1 = fmaf(wgt, r.y, o1);
    }
    atomicAdd(&outer[2 * t], o0);
    atomicAdd(&outer[2 * t + 1], o1);
}

// ============ classifier: pred = sigmoid(outer/Z2 . v + bc . wout + bout) ====
__global__ __launch_bounds__(256) void k_cls(
    const float* __restrict__ outer, const float* __restrict__ Z2,
    const float* __restrict__ v, const float* __restrict__ bc,
    const float* __restrict__ wout, const float* __restrict__ bout,
    float* __restrict__ out)
{
    __shared__ float pp[4];
    const int t = threadIdx.x;
    const float z2inv = 1.f / Z2[0];
    float p = (outer[2 * t] * v[2 * t] + outer[2 * t + 1] * v[2 * t + 1]) * z2inv
            + bc[2 * t] * wout[2 * t] + bc[2 * t + 1] * wout[2 * t + 1];
    #pragma unroll
    for (int m = 1; m < 64; m <<= 1) p += __shfl_xor(p, m);
    if ((t & 63) == 0) pp[t >> 6] = p;
    __syncthreads();
    if (t == 0) {
        float s = pp[0] + pp[1] + pp[2] + pp[3] + bout[0];
        out[0] = 1.f / (1.f + __expf(-s));
    }
}

extern "C" void kernel_launch(void* const* d_in, const int* in_sizes, int n_in,
                              void* d_out, int out_size, void* d_ws, size_t ws_size,
                              hipStream_t stream)
{
    const float* emb  = (const float*)d_in[0];
    const int*   lab  = (const int*)d_in[1];
    const float* Wa1  = (const float*)d_in[2];
    const float* ba1  = (const float*)d_in[3];
    const float* wo1  = (const float*)d_in[4];
    const float* bo1  = (const float*)d_in[5];
    const float* Wa2  = (const float*)d_in[6];
    const float* ba2  = (const float*)d_in[7];
    const float* wo2  = (const float*)d_in[8];
    const float* bo2  = (const float*)d_in[9];
    const float* Wc   = (const float*)d_in[10];
    const float* bc   = (const float*)d_in[11];
    const float* wout = (const float*)d_in[12];
    const float* bout = (const float*)d_in[13];

    float* ws    = (float*)d_ws;
    float* Z1s   = ws + 0;        // 32 shards
    float* Z2    = ws + 32;
    float* v     = ws + 64;
    float* e2    = ws + 1024;
    float* outer = ws + 1536;
    unsigned short* Wt = (unsigned short*)(ws + 4096);
    float* rawr  = ws + 36864;

    // replica count: 8 if workspace allows (XCD-local atomics), else 1
    const size_t need8 = ((size_t)36864 + 8u * NBAGS * D_EMB) * sizeof(float);
    const int R = (ws_size >= need8) ? 8 : 1;

    // zero scalars + replica accumulators (harness does not re-poison)
    hipMemsetAsync(d_ws, 0, ((size_t)36864 + (size_t)R * NBAGS * D_EMB) * sizeof(float), stream);

    hipLaunchKernelGGL(k_prep_wt, dim3(ATT),   dim3(256), 0, stream, Wa1, Wt);
    hipLaunchKernelGGL(k_v,       dim3(64),    dim3(256), 0, stream, Wc, wout, v);
    hipLaunchKernelGGL(k_att1,    dim3(NBLK),  dim3(256), 0, stream,
                       emb, lab, Wt, ba1, wo1, bo1, rawr, R, Z1s);
    hipLaunchKernelGGL(k_att2,    dim3(NBAGS), dim3(128), 0, stream,
                       Wa2, ba2, wo2, bo2, rawr, R, Z1s, e2, Z2);
    hipLaunchKernelGGL(k_pool,    dim3(8),     dim3(256), 0, stream,
                       rawr, e2, outer);
    hipLaunchKernelGGL(k_cls,     dim3(1),     dim3(256), 0, stream,
                       outer, Z2, v, bc, wout, bout, (float*)d_out);
}